// Round 19
// baseline (776.892 us; speedup 1.0000x reference)
//
#include <hip/hip_runtime.h>
#include <hip/hip_bf16.h>
#include <math.h>

#define PP 22
#define HH 64
#define NL 4
#define NE 462     // 22*21 directed edges, r-major: e = r*22 + a
#define NTILE 29   // ceil(462/16)
#define SST 68     // float stride for node-feature rows (sh, sSeg)
#define SSTH 72    // ushort stride for bf16 Apre/Bpre rows (144B, 16B-aligned)
#define NG 2       // graphs per block

typedef __attribute__((ext_vector_type(8))) short bf16x8;
typedef __attribute__((ext_vector_type(4))) float f32x4;

#define MFMA(A, B, C) __builtin_amdgcn_mfma_f32_16x16x32_bf16(A, B, C, 0, 0, 0)
#define PHI(mt, r) ((((mt) >> 1) << 5) + (((r) >> 2) << 3) + (((mt) & 1) << 2) + ((r) & 3))

__device__ __forceinline__ float silu_f(float v) { return v / (1.0f + __expf(-v)); }

__device__ __forceinline__ unsigned short f2bf(float x) {
    __hip_bfloat16 h = __float2bfloat16(x);
    unsigned short u;
    __builtin_memcpy(&u, &h, 2);
    return u;
}
__device__ __forceinline__ float bf2fs(unsigned short h) {
    return __uint_as_float(((unsigned int)h) << 16);
}
__device__ __forceinline__ float bfbits(unsigned int u, int hi) {
    return __uint_as_float(((u >> (hi * 16)) & 0xffffu) << 16);
}

#define LD8(dst, PTR) { \
    float4 _a = *(const float4*)(PTR); float4 _b = *(const float4*)((PTR) + 4); \
    dst[0]=_a.x; dst[1]=_a.y; dst[2]=_a.z; dst[3]=_a.w; \
    dst[4]=_b.x; dst[5]=_b.y; dst[6]=_b.z; dst[7]=_b.w; }

// ---------------------------------------------------------------------------
// Weight prep (unchanged): hi-only bf16 frag blocks, 512 ushorts each.
//  0-7 W1a | 8-15 W1b | 16-23 W2 phi | 24-31 CM1 | 32-39 CC1 | 40-55 NW1 phi | 56-63 NW2
// ---------------------------------------------------------------------------
__global__ __launch_bounds__(64) void prep_w(
    const float* __restrict__ edge_w1, const float* __restrict__ edge_w2,
    const float* __restrict__ cm_w1, const float* __restrict__ cc_w1,
    const float* __restrict__ node_w1, const float* __restrict__ node_w2,
    unsigned short* __restrict__ ws)
{
    int blk = blockIdx.x;
    int l = blk >> 6, moff = blk & 63;
    int lane = threadIdx.x, n0 = lane & 15, kg = lane >> 4;
    const float* base; int col, kt;
    if (moff < 8)       { kt = moff >> 2;              int nt = moff & 3;        base = edge_w1 + l * 130 * HH;           col = nt * 16 + n0; }
    else if (moff < 16) { int m = moff - 8;  kt = m >> 2; int nt = m & 3;        base = edge_w1 + l * 130 * HH + 64 * HH; col = nt * 16 + n0; }
    else if (moff < 24) { int m = moff - 16; kt = m >> 2; int mt = m & 3;        base = edge_w2 + l * HH * HH;            col = PHI(mt, n0); }
    else if (moff < 32) { int m = moff - 24; kt = m >> 2; int nt = m & 3;        base = cm_w1 + l * HH * HH;              col = nt * 16 + n0; }
    else if (moff < 40) { int m = moff - 32; kt = m >> 2; int nt = m & 3;        base = cc_w1 + l * HH * HH;              col = nt * 16 + n0; }
    else if (moff < 56) { int m = moff - 40; kt = m >> 2; int mt = m & 3;        base = node_w1 + l * 128 * HH;           col = PHI(mt, n0); }
    else                { int m = moff - 56; kt = m >> 2; int nt = m & 3;        base = node_w2 + l * HH * HH;            col = nt * 16 + n0; }
    int k0 = kt * 32 + kg * 8;
    unsigned short* d = ws + blk * 512 + lane * 8;
#pragma unroll
    for (int j = 0; j < 8; ++j) d[j] = f2bf(base[(k0 + j) * HH + col]);
}

// ---------------------------------------------------------------------------
// Main kernel: TWO graphs per block, 512 threads (8 waves: 4 per graph),
// ~65KB LDS -> 2 blocks/CU = 16 waves/CU (schedulable LDS pool is ~144-152KB,
// not 160: R18's 74.5KB blocks did NOT pair; R13's 143KB single block ran).
// Apre/Bpre stored as bf16 (stride-72 rows): -11.3KB LDS and halved av/bv
// edge-loop reads. 128-reg recipe from R15/R18 untouched
// (__launch_bounds__(512,1); explicit min-waves hints >=2 cause spill).
// ---------------------------------------------------------------------------
__global__ __launch_bounds__(512, 1) void egnn_kernel(
    const float* __restrict__ input, const float* __restrict__ timev,
    const float* __restrict__ emb_w, const float* __restrict__ emb_b,
    const float* __restrict__ edge_w1, const float* __restrict__ edge_b1,
    const float* __restrict__ edge_b2,
    const float* __restrict__ node_b1, const float* __restrict__ node_b2,
    const float* __restrict__ cm_b1, const float* __restrict__ cm_w2,
    const float* __restrict__ cc_b1, const float* __restrict__ cc_w2,
    const unsigned short* __restrict__ wfr,
    float* __restrict__ out)
{
    const int g0   = blockIdx.x * NG;
    const int tid  = threadIdx.x;
    const int w    = tid >> 6;     // wave 0..7
    const int lw   = w & 3;        // wave-local within graph
    const int gi   = w >> 2;       // graph index 0..1
    const int lane = tid & 63;
    const int n0   = lane & 15;
    const int kg   = lane >> 4;

    __shared__ __align__(16) unsigned short wlds[12288];   // 24KB staging
    __shared__ __align__(16) unsigned short sApre[NG][PP][SSTH];  // bf16
    __shared__ __align__(16) unsigned short sBpre[NG][PP][SSTH];  // bf16
    __shared__ float sh[NG][PP][SST], sSeg[NG][PP][SST];
    __shared__ __align__(16) float sx[NG][PP][4];
    __shared__ __align__(16) float sx0[NG][PP][4];
    __shared__ float sTr[NG][PP][4];
    __shared__ float sW128[HH], sW129[HH];
    __shared__ float sBp[128];              // [0..63] b2[PHI], [64..127] nb1[PHI]
    __shared__ unsigned int sHCp[4][32];    // packed bf16 pairs: cmb,ccb,cm2,cc2
    __shared__ float smean[NG][3];

#define STAGE(SRC, N16) { const uint4* _s = (const uint4*)(SRC); uint4* _d = (uint4*)wlds; \
    for (int idx = tid; idx < (N16); idx += 512) _d[idx] = _s[idx]; }

    // ---- init ----
    if (tid < NG * PP * 3) {
        int gg = tid / (PP * 3), j = tid % (PP * 3);
        float v = input[(g0 + gg) * (PP * 3) + j];
        sx0[gg][j / 3][j % 3] = v;
        sx [gg][j / 3][j % 3] = v;
    }
    if (tid < NG * PP) { int gg = tid / PP, p = tid % PP; sx0[gg][p][3] = 0.f; sx[gg][p][3] = 0.f; }
    {
        float tg = timev[g0 + gi];
        for (int i = lw; i < PP; i += 4)
            sh[gi][i][lane] = emb_w[i * HH + lane] + tg * emb_w[PP * HH + lane] + emb_b[lane];
    }
    for (int idx = tid; idx < NG * PP * SST; idx += 512) (&sSeg[0][0][0])[idx] = 0.f;
    if (tid < NG * PP * 4) (&sTr[0][0][0])[tid] = 0.f;
    __syncthreads();

    for (int l = 0; l < NL; ++l) {
        const unsigned short* wfl = wfr + (size_t)l * 32768;

        // ===== [1] stage W1a/W1b frags (16KB) + per-layer constants =====
        STAGE(wfl, 1024);
        if (tid < HH)               sW128[tid]        = edge_w1[(l * 130 + 128) * HH + tid];
        else if (tid < 2 * HH)      sW129[tid - HH]   = edge_w1[(l * 130 + 129) * HH + tid - HH];
        else if (tid < 2 * HH + 128) {
            int t2 = tid - 2 * HH;
            int i = t2 & 63, mt = i >> 4, r = i & 15;
            int phi = PHI(mt, r);
            sBp[t2] = (t2 < 64) ? edge_b2[l * HH + phi] : node_b1[l * HH + phi];
        } else if (tid < 2 * HH + 128 + 128) {
            int t3 = tid - (2 * HH + 128);          // 0..127
            int arr = t3 >> 5, j = t3 & 31;
            const float* src = (arr == 0) ? cm_b1 : (arr == 1) ? cc_b1 : (arr == 2) ? cm_w2 : cc_w2;
            sHCp[arr][j] = (unsigned)f2bf(src[l * HH + 2 * j])
                         | ((unsigned)f2bf(src[l * HH + 2 * j + 1]) << 16);
        }
        __syncthreads();  // s1

        // ===== [2] Apre/Bpre via MFMA (stored bf16): (mtn, mat)=(lw&1,lw>>1)
        {
            int mtn = lw & 1, mat = lw >> 1;
            int node = mtn * 16 + n0;
            bool vn = node < PP;
            int crow = vn ? node : 0;
            bf16x8 hhi[2];
#pragma unroll
            for (int kt = 0; kt < 2; ++kt) {
                float vv[8];
                LD8(vv, &sh[gi][crow][kt * 32 + kg * 8]);
#pragma unroll
                for (int j = 0; j < 8; ++j)
                    hhi[kt][j] = (short)f2bf(vn ? vv[j] : 0.f);
            }
#pragma unroll
            for (int ntf = 0; ntf < 4; ++ntf) {
                f32x4 acc = (f32x4){0.f, 0.f, 0.f, 0.f};
#pragma unroll
                for (int kt = 0; kt < 2; ++kt) {
                    bf16x8 wv = *(const bf16x8*)&wlds[(mat * 8 + kt * 4 + ntf) * 512 + lane * 8];
                    acc = MFMA(hhi[kt], wv, acc);
                }
                int col = ntf * 16 + n0;
                float b1v = edge_b1[l * HH + col];
#pragma unroll
                for (int q = 0; q < 4; ++q) {
                    int m = mtn * 16 + kg * 4 + q;
                    if (m < PP) {
                        if (mat == 0) sApre[gi][m][col] = f2bf(acc[q] + b1v);
                        else          sBpre[gi][m][col] = f2bf(acc[q]);
                    }
                }
            }
        }
        __syncthreads();  // s2

        // ===== [2b] stage edge frags W2/CM1/CC1 (24KB) =====
        STAGE(wfl + 16 * 512, 1536);
        __syncthreads();  // s2b

        // ---- register-resident edge weights (96 regs) + head consts (32) ----
        bf16x8 wE2r[2][4], wCMr[2][4], wCCr[2][4];
#pragma unroll
        for (int kt = 0; kt < 2; ++kt)
#pragma unroll
            for (int mt = 0; mt < 4; ++mt) {
                wE2r[kt][mt] = *(const bf16x8*)&wlds[(kt * 4 + mt) * 512 + lane * 8];
                wCMr[kt][mt] = *(const bf16x8*)&wlds[(8 + kt * 4 + mt) * 512 + lane * 8];
                wCCr[kt][mt] = *(const bf16x8*)&wlds[(16 + kt * 4 + mt) * 512 + lane * 8];
            }
        unsigned int bP[4][4][2];
#pragma unroll
        for (int arr = 0; arr < 4; ++arr)
#pragma unroll
            for (int nt = 0; nt < 4; ++nt) {
                bP[arr][nt][0] = sHCp[arr][nt * 8 + kg * 2];
                bP[arr][nt][1] = sHCp[arr][nt * 8 + kg * 2 + 1];
            }

        // ===== [3] edge phase =====
        for (int jt = lw; jt < NTILE; jt += 4) {
            int e0 = jt * 16;
            int e = e0 + n0;
            bool vr = e < NE;
            int ec = vr ? e : (NE - 1);
            int a = ec % PP, r = ec / PP;
            int b = (r < a) ? r : r + 1;
            float4 xa = *(const float4*)&sx[gi][a][0];
            float4 xb = *(const float4*)&sx[gi][b][0];
            float4 oa = *(const float4*)&sx0[gi][a][0];
            float4 ob = *(const float4*)&sx0[gi][b][0];
            float dx = xa.x - xb.x, dy = xa.y - xb.y, dz = xa.z - xb.z;
            float rad = dx * dx + dy * dy + dz * dz;
            float ex = oa.x - ob.x, ey = oa.y - ob.y, ez = oa.z - ob.z;
            float ea = ex * ex + ey * ey + ez * ez;
            float inv = 1.0f / (sqrtf(rad + 1e-8f) + 1.0f);
            float cdx = dx * inv, cdy = dy * inv, cdz = dz * inv;
            float cx = xa.y * xb.z - xa.z * xb.y;
            float cy = xa.z * xb.x - xa.x * xb.z;
            float cz = xa.x * xb.y - xa.y * xb.x;
            float cn = 1.0f / (sqrtf(cx * cx + cy * cy + cz * cz + 1e-8f) + 1.0f);
            float crx = cx * cn, cry = cy * cn, crz = cz * cn;

            // ---- E2 (swapped, phi rows): lane n0 = its edge column ----
            f32x4 acc[4];
#pragma unroll
            for (int mt = 0; mt < 4; ++mt) acc[mt] = (f32x4){0.f, 0.f, 0.f, 0.f};
#pragma unroll
            for (int kt = 0; kt < 2; ++kt) {
                int base = kt * 32 + kg * 8;
                bf16x8 av16 = *(const bf16x8*)&sApre[gi][a][base];
                bf16x8 bv16 = *(const bf16x8*)&sBpre[gi][b][base];
                float w8[8], w9[8];
                LD8(w8, &sW128[base]);
                LD8(w9, &sW129[base]);
                bf16x8 zhi;
#pragma unroll
                for (int j8 = 0; j8 < 8; ++j8) {
                    float avf = bf2fs((unsigned short)av16[j8]);
                    float bvf = bf2fs((unsigned short)bv16[j8]);
                    float z = avf + bvf + rad * w8[j8] + ea * w9[j8];
                    zhi[j8] = (short)f2bf(silu_f(z));
                }
#pragma unroll
                for (int mt = 0; mt < 4; ++mt)
                    acc[mt] = MFMA(wE2r[kt][mt], zhi, acc[mt]);
            }
            // epilogue: silu+bias, mask, seg atomics (distinct rows), pack hi
            unsigned short pkE[4][4];
#pragma unroll
            for (int mt = 0; mt < 4; ++mt) {
                int phib = ((mt >> 1) << 5) + (kg << 3) + ((mt & 1) << 2);
#pragma unroll
                for (int q = 0; q < 4; ++q) {
                    float v = silu_f(acc[mt][q] + sBp[mt * 16 + kg * 4 + q]);
                    v = vr ? v : 0.f;
                    pkE[mt][q] = f2bf(v);
                    if (vr) atomicAdd(&sSeg[gi][a][phib + q], v);
                }
            }
            // ---- E3 B-frags (EF as B operand): register relabel of pkE ----
            bf16x8 ehi[2];
#pragma unroll
            for (int kt = 0; kt < 2; ++kt)
#pragma unroll
                for (int j8 = 0; j8 < 8; ++j8)
                    ehi[kt][j8] = (short)pkE[kt * 2 + (j8 >> 2)][j8 & 3];

            // ---- E3 (operand-swapped): am[q] = cm1[edge n0][nt*16+kg*4+q] ----
            float pm = 0.f, pc = 0.f;
#pragma unroll
            for (int nt = 0; nt < 4; ++nt) {
                f32x4 am = (f32x4){0.f, 0.f, 0.f, 0.f};
                f32x4 ac = (f32x4){0.f, 0.f, 0.f, 0.f};
#pragma unroll
                for (int kt = 0; kt < 2; ++kt) {
                    am = MFMA(wCMr[kt][nt], ehi[kt], am);
                    ac = MFMA(wCCr[kt][nt], ehi[kt], ac);
                }
#pragma unroll
                for (int q = 0; q < 4; ++q) {
                    int hi = q & 1, pj = q >> 1;
                    float cmb = bfbits(bP[0][nt][pj], hi);
                    float ccb = bfbits(bP[1][nt][pj], hi);
                    float cm2 = bfbits(bP[2][nt][pj], hi);
                    float cc2 = bfbits(bP[3][nt][pj], hi);
                    pm += silu_f(am[q] + cmb) * cm2;
                    pc += silu_f(ac[q] + ccb) * cc2;
                }
            }
            // reduce across kg groups only (lane bits 4,5)
            pm += __shfl_xor(pm, 16, 64);
            pm += __shfl_xor(pm, 32, 64);
            pc += __shfl_xor(pc, 16, 64);
            pc += __shfl_xor(pc, 32, 64);
            if (kg == 0 && vr) {
                atomicAdd(&sTr[gi][a][0], cdx * pm + pc * crx);
                atomicAdd(&sTr[gi][a][1], cdy * pm + pc * cry);
                atomicAdd(&sTr[gi][a][2], cdz * pm + pc * crz);
            }
            // anti-pipelining fence (R12: removal -> 1.4GB scratch spill)
            __builtin_amdgcn_sched_barrier(0);
        }
        __syncthreads();  // s3

        // ===== [4] stage node frags NW1/NW2 (24KB) =====
        STAGE(wfl + 40 * 512, 1536);
        __syncthreads();  // s4

        // ===== [5] node MLP stage 1 (swapped, phi rows) =====
        unsigned short pkN[4][4];
        {
            int mtn = lw >> 1;
            int node = mtn * 16 + n0;
            bool vn = node < PP;
            int crow = vn ? node : 0;
            f32x4 acc[4];
#pragma unroll
            for (int mt = 0; mt < 4; ++mt) acc[mt] = (f32x4){0.f, 0.f, 0.f, 0.f};
#pragma unroll
            for (int kt = 0; kt < 4; ++kt) {
                const float* srcp = (kt < 2) ? &sh[gi][crow][kt * 32 + kg * 8]
                                             : &sSeg[gi][crow][(kt - 2) * 32 + kg * 8];
                float vv[8];
                LD8(vv, srcp);
                bf16x8 bhi;
#pragma unroll
                for (int j8 = 0; j8 < 8; ++j8)
                    bhi[j8] = (short)f2bf(vn ? vv[j8] : 0.f);
#pragma unroll
                for (int mt = 0; mt < 4; ++mt) {
                    bf16x8 wv = *(const bf16x8*)&wlds[(kt * 4 + mt) * 512 + lane * 8];
                    acc[mt] = MFMA(wv, bhi, acc[mt]);
                }
            }
#pragma unroll
            for (int mt = 0; mt < 4; ++mt)
#pragma unroll
                for (int q = 0; q < 4; ++q)
                    pkN[mt][q] = f2bf(silu_f(acc[mt][q] + sBp[64 + mt * 16 + kg * 4 + q]));
        }
        __syncthreads();  // s5

        // ===== [6] node MLP stage 2 + h/x update + cleanup =====
        {
            bf16x8 mh[2];
#pragma unroll
            for (int kt = 0; kt < 2; ++kt)
#pragma unroll
                for (int j8 = 0; j8 < 8; ++j8)
                    mh[kt][j8] = (short)pkN[kt * 2 + (j8 >> 2)][j8 & 3];
            int mtn = lw >> 1;
#pragma unroll
            for (int t = 0; t < 2; ++t) {
                int ntf = (lw & 1) * 2 + t;
                f32x4 acc = (f32x4){0.f, 0.f, 0.f, 0.f};
#pragma unroll
                for (int kt = 0; kt < 2; ++kt) {
                    bf16x8 wv = *(const bf16x8*)&wlds[(16 + kt * 4 + ntf) * 512 + lane * 8];
                    acc = MFMA(mh[kt], wv, acc);
                }
                int col = ntf * 16 + n0;
                float nb2 = node_b2[l * HH + col];
#pragma unroll
                for (int q = 0; q < 4; ++q) {
                    int m = mtn * 16 + kg * 4 + q;
                    if (m < PP) sh[gi][m][col] += acc[q] + nb2;
                }
            }
        }
        if (tid < NG * PP * 4) {
            int gg = tid / (PP * 4), j = tid % (PP * 4);
            int p = j >> 2, d = j & 3;
            float v = sTr[gg][p][d];
            if (d < 3) sx[gg][p][d] += v;
            sTr[gg][p][d] = 0.f;
        }
        for (int idx = tid; idx < NG * PP * SST; idx += 512) (&sSeg[0][0][0])[idx] = 0.f;
        __syncthreads();  // s6: protect wlds/sSeg/sTr before next layer
    }

    // ---- output: vel = (x - x0) - mean_p(x - x0), all graphs ----
    if (tid < NG * 3) {
        int gg = tid / 3, d = tid % 3;
        float s = 0.0f;
        for (int p = 0; p < PP; ++p) s += sx[gg][p][d] - sx0[gg][p][d];
        smean[gg][d] = s / (float)PP;
    }
    __syncthreads();
    if (tid < NG * PP * 3) {
        int gg = tid / (PP * 3), j = tid % (PP * 3);
        int p = j / 3, d = j % 3;
        out[(g0 + gg) * (PP * 3) + j] = (sx[gg][p][d] - sx0[gg][p][d]) - smean[gg][d];
    }
#undef STAGE
}

extern "C" void kernel_launch(void* const* d_in, const int* in_sizes, int n_in,
                              void* d_out, int out_size, void* d_ws, size_t ws_size,
                              hipStream_t stream) {
    const float* input   = (const float*)d_in[0];
    const float* timev   = (const float*)d_in[1];
    const float* emb_w   = (const float*)d_in[2];
    const float* emb_b   = (const float*)d_in[3];
    const float* edge_w1 = (const float*)d_in[4];
    const float* edge_b1 = (const float*)d_in[5];
    const float* edge_w2 = (const float*)d_in[6];
    const float* edge_b2 = (const float*)d_in[7];
    const float* node_w1 = (const float*)d_in[8];
    const float* node_b1 = (const float*)d_in[9];
    const float* node_w2 = (const float*)d_in[10];
    const float* node_b2 = (const float*)d_in[11];
    const float* cm_w1   = (const float*)d_in[12];
    const float* cm_b1   = (const float*)d_in[13];
    const float* cm_w2   = (const float*)d_in[14];
    const float* cc_w1   = (const float*)d_in[15];
    const float* cc_b1   = (const float*)d_in[16];
    const float* cc_w2   = (const float*)d_in[17];
    // d_in[18]=row, d_in[19]=col: deterministic fully-connected edges, recomputed in-kernel

    unsigned short* wsu = (unsigned short*)d_ws;
    prep_w<<<dim3(NL * 64), dim3(64), 0, stream>>>(edge_w1, edge_w2, cm_w1, cc_w1,
                                                   node_w1, node_w2, wsu);

    float* out = (float*)d_out;
    egnn_kernel<<<dim3(1024 / NG), dim3(512), 0, stream>>>(
        input, timev, emb_w, emb_b, edge_w1, edge_b1, edge_b2,
        node_b1, node_b2, cm_b1, cm_w2, cc_b1, cc_w2, wsu, out);
}

// Round 20
// 748.946 us; speedup vs baseline: 1.0373x; 1.0373x over previous
//
#include <hip/hip_runtime.h>
#include <hip/hip_bf16.h>
#include <math.h>

#define PP 22
#define HH 64
#define NL 4
#define NE 462     // 22*21 directed edges, r-major: e = r*22 + a
#define NTILE 29   // ceil(462/16)
#define SST 68     // float stride for node-feature rows (sh, sSeg)
#define SSTH 72    // ushort stride for bf16 Apre/Bpre rows
#define NG 2       // graphs per block

typedef __attribute__((ext_vector_type(8))) short bf16x8;
typedef __attribute__((ext_vector_type(4))) float f32x4;

#define MFMA(A, B, C) __builtin_amdgcn_mfma_f32_16x16x32_bf16(A, B, C, 0, 0, 0)
#define PHI(mt, r) ((((mt) >> 1) << 5) + (((r) >> 2) << 3) + (((mt) & 1) << 2) + ((r) & 3))

// fast silu: v_exp + v_rcp (hardware approx, ~2^-22 rel err) instead of the
// 8-op IEEE division sequence clang emits for '/' without fast-math.
__device__ __forceinline__ float silu_f(float v) {
    return v * __builtin_amdgcn_rcpf(1.0f + __expf(-v));
}

__device__ __forceinline__ unsigned short f2bf(float x) {
    __hip_bfloat16 h = __float2bfloat16(x);
    unsigned short u;
    __builtin_memcpy(&u, &h, 2);
    return u;
}
__device__ __forceinline__ float bf2fs(unsigned short h) {
    return __uint_as_float(((unsigned int)h) << 16);
}
__device__ __forceinline__ float bfbits(unsigned int u, int hi) {
    return __uint_as_float(((u >> (hi * 16)) & 0xffffu) << 16);
}

#define LD8(dst, PTR) { \
    float4 _a = *(const float4*)(PTR); float4 _b = *(const float4*)((PTR) + 4); \
    dst[0]=_a.x; dst[1]=_a.y; dst[2]=_a.z; dst[3]=_a.w; \
    dst[4]=_b.x; dst[5]=_b.y; dst[6]=_b.z; dst[7]=_b.w; }

// ---------------------------------------------------------------------------
// Weight prep (unchanged): hi-only bf16 frag blocks, 512 ushorts each.
//  0-7 W1a | 8-15 W1b | 16-23 W2 phi | 24-31 CM1 | 32-39 CC1 | 40-55 NW1 phi | 56-63 NW2
// ---------------------------------------------------------------------------
__global__ __launch_bounds__(64) void prep_w(
    const float* __restrict__ edge_w1, const float* __restrict__ edge_w2,
    const float* __restrict__ cm_w1, const float* __restrict__ cc_w1,
    const float* __restrict__ node_w1, const float* __restrict__ node_w2,
    unsigned short* __restrict__ ws)
{
    int blk = blockIdx.x;
    int l = blk >> 6, moff = blk & 63;
    int lane = threadIdx.x, n0 = lane & 15, kg = lane >> 4;
    const float* base; int col, kt;
    if (moff < 8)       { kt = moff >> 2;              int nt = moff & 3;        base = edge_w1 + l * 130 * HH;           col = nt * 16 + n0; }
    else if (moff < 16) { int m = moff - 8;  kt = m >> 2; int nt = m & 3;        base = edge_w1 + l * 130 * HH + 64 * HH; col = nt * 16 + n0; }
    else if (moff < 24) { int m = moff - 16; kt = m >> 2; int mt = m & 3;        base = edge_w2 + l * HH * HH;            col = PHI(mt, n0); }
    else if (moff < 32) { int m = moff - 24; kt = m >> 2; int nt = m & 3;        base = cm_w1 + l * HH * HH;              col = nt * 16 + n0; }
    else if (moff < 40) { int m = moff - 32; kt = m >> 2; int nt = m & 3;        base = cc_w1 + l * HH * HH;              col = nt * 16 + n0; }
    else if (moff < 56) { int m = moff - 40; kt = m >> 2; int mt = m & 3;        base = node_w1 + l * 128 * HH;           col = PHI(mt, n0); }
    else                { int m = moff - 56; kt = m >> 2; int nt = m & 3;        base = node_w2 + l * HH * HH;            col = nt * 16 + n0; }
    int k0 = kt * 32 + kg * 8;
    unsigned short* d = ws + blk * 512 + lane * 8;
#pragma unroll
    for (int j = 0; j < 8; ++j) d[j] = f2bf(base[(k0 + j) * HH + col]);
}

// ---------------------------------------------------------------------------
// Main kernel: TWO graphs per block, 512 threads (8 waves: 4 per graph),
// ~64KB LDS. Unified reg usage (VGPR 128 + AGPR-resident weight preload)
// caps at 2 waves/SIMD -> per-wave VALU/chain length is the lever now:
// fast-rcp silu (11 -> 5 VALU ops), hoisted packed-bf16 b2 biases.
// __launch_bounds__(512,1): the only bound producing the clean 128-reg
// no-spill allocation (min-waves hints >=2 cause allocator spill).
// ---------------------------------------------------------------------------
__global__ __launch_bounds__(512, 1) void egnn_kernel(
    const float* __restrict__ input, const float* __restrict__ timev,
    const float* __restrict__ emb_w, const float* __restrict__ emb_b,
    const float* __restrict__ edge_w1, const float* __restrict__ edge_b1,
    const float* __restrict__ edge_b2,
    const float* __restrict__ node_b1, const float* __restrict__ node_b2,
    const float* __restrict__ cm_b1, const float* __restrict__ cm_w2,
    const float* __restrict__ cc_b1, const float* __restrict__ cc_w2,
    const unsigned short* __restrict__ wfr,
    float* __restrict__ out)
{
    const int g0   = blockIdx.x * NG;
    const int tid  = threadIdx.x;
    const int w    = tid >> 6;     // wave 0..7
    const int lw   = w & 3;        // wave-local within graph
    const int gi   = w >> 2;       // graph index 0..1
    const int lane = tid & 63;
    const int n0   = lane & 15;
    const int kg   = lane >> 4;

    __shared__ __align__(16) unsigned short wlds[12288];   // 24KB staging
    __shared__ __align__(16) unsigned short sApre[NG][PP][SSTH];  // bf16
    __shared__ __align__(16) unsigned short sBpre[NG][PP][SSTH];  // bf16
    __shared__ float sh[NG][PP][SST], sSeg[NG][PP][SST];
    __shared__ __align__(16) float sx[NG][PP][4];
    __shared__ __align__(16) float sx0[NG][PP][4];
    __shared__ float sTr[NG][PP][4];
    __shared__ float sW128[HH], sW129[HH];
    __shared__ float sBp[128];              // [0..63] b2[PHI], [64..127] nb1[PHI]
    __shared__ unsigned int sB2p[32];       // packed bf16 pairs of b2[PHI]
    __shared__ unsigned int sHCp[4][32];    // packed bf16 pairs: cmb,ccb,cm2,cc2
    __shared__ float smean[NG][3];

#define STAGE(SRC, N16) { const uint4* _s = (const uint4*)(SRC); uint4* _d = (uint4*)wlds; \
    for (int idx = tid; idx < (N16); idx += 512) _d[idx] = _s[idx]; }

    // ---- init ----
    if (tid < NG * PP * 3) {
        int gg = tid / (PP * 3), j = tid % (PP * 3);
        float v = input[(g0 + gg) * (PP * 3) + j];
        sx0[gg][j / 3][j % 3] = v;
        sx [gg][j / 3][j % 3] = v;
    }
    if (tid < NG * PP) { int gg = tid / PP, p = tid % PP; sx0[gg][p][3] = 0.f; sx[gg][p][3] = 0.f; }
    {
        float tg = timev[g0 + gi];
        for (int i = lw; i < PP; i += 4)
            sh[gi][i][lane] = emb_w[i * HH + lane] + tg * emb_w[PP * HH + lane] + emb_b[lane];
    }
    for (int idx = tid; idx < NG * PP * SST; idx += 512) (&sSeg[0][0][0])[idx] = 0.f;
    if (tid < NG * PP * 4) (&sTr[0][0][0])[tid] = 0.f;
    __syncthreads();

    for (int l = 0; l < NL; ++l) {
        const unsigned short* wfl = wfr + (size_t)l * 32768;

        // ===== [1] stage W1a/W1b frags (16KB) + per-layer constants =====
        STAGE(wfl, 1024);
        if (tid < HH)               sW128[tid]        = edge_w1[(l * 130 + 128) * HH + tid];
        else if (tid < 2 * HH)      sW129[tid - HH]   = edge_w1[(l * 130 + 129) * HH + tid - HH];
        else if (tid < 2 * HH + 128) {
            int t2 = tid - 2 * HH;
            int i = t2 & 63, mt = i >> 4, r = i & 15;
            int phi = PHI(mt, r);
            sBp[t2] = (t2 < 64) ? edge_b2[l * HH + phi] : node_b1[l * HH + phi];
        } else if (tid < 2 * HH + 128 + 128) {
            int t3 = tid - (2 * HH + 128);          // 0..127
            int arr = t3 >> 5, j = t3 & 31;
            const float* src = (arr == 0) ? cm_b1 : (arr == 1) ? cc_b1 : (arr == 2) ? cm_w2 : cc_w2;
            sHCp[arr][j] = (unsigned)f2bf(src[l * HH + 2 * j])
                         | ((unsigned)f2bf(src[l * HH + 2 * j + 1]) << 16);
        } else if (tid < 2 * HH + 128 + 128 + 32) {
            int j = tid - (2 * HH + 128 + 128);     // 0..31: pack b2[PHI] pairs
            int i0 = 2 * j, i1 = 2 * j + 1;
            int phi0 = PHI(i0 >> 4, i0 & 15), phi1 = PHI(i1 >> 4, i1 & 15);
            sB2p[j] = (unsigned)f2bf(edge_b2[l * HH + phi0])
                    | ((unsigned)f2bf(edge_b2[l * HH + phi1]) << 16);
        }
        __syncthreads();  // s1

        // ===== [2] Apre/Bpre via MFMA (stored bf16): (mtn, mat)=(lw&1,lw>>1)
        {
            int mtn = lw & 1, mat = lw >> 1;
            int node = mtn * 16 + n0;
            bool vn = node < PP;
            int crow = vn ? node : 0;
            bf16x8 hhi[2];
#pragma unroll
            for (int kt = 0; kt < 2; ++kt) {
                float vv[8];
                LD8(vv, &sh[gi][crow][kt * 32 + kg * 8]);
#pragma unroll
                for (int j = 0; j < 8; ++j)
                    hhi[kt][j] = (short)f2bf(vn ? vv[j] : 0.f);
            }
#pragma unroll
            for (int ntf = 0; ntf < 4; ++ntf) {
                f32x4 acc = (f32x4){0.f, 0.f, 0.f, 0.f};
#pragma unroll
                for (int kt = 0; kt < 2; ++kt) {
                    bf16x8 wv = *(const bf16x8*)&wlds[(mat * 8 + kt * 4 + ntf) * 512 + lane * 8];
                    acc = MFMA(hhi[kt], wv, acc);
                }
                int col = ntf * 16 + n0;
                float b1v = edge_b1[l * HH + col];
#pragma unroll
                for (int q = 0; q < 4; ++q) {
                    int m = mtn * 16 + kg * 4 + q;
                    if (m < PP) {
                        if (mat == 0) sApre[gi][m][col] = f2bf(acc[q] + b1v);
                        else          sBpre[gi][m][col] = f2bf(acc[q]);
                    }
                }
            }
        }
        __syncthreads();  // s2

        // ===== [2b] stage edge frags W2/CM1/CC1 (24KB) =====
        STAGE(wfl + 16 * 512, 1536);
        __syncthreads();  // s2b

        // ---- register-resident edge weights + packed consts ----
        bf16x8 wE2r[2][4], wCMr[2][4], wCCr[2][4];
#pragma unroll
        for (int kt = 0; kt < 2; ++kt)
#pragma unroll
            for (int mt = 0; mt < 4; ++mt) {
                wE2r[kt][mt] = *(const bf16x8*)&wlds[(kt * 4 + mt) * 512 + lane * 8];
                wCMr[kt][mt] = *(const bf16x8*)&wlds[(8 + kt * 4 + mt) * 512 + lane * 8];
                wCCr[kt][mt] = *(const bf16x8*)&wlds[(16 + kt * 4 + mt) * 512 + lane * 8];
            }
        unsigned int bP[4][4][2];
#pragma unroll
        for (int arr = 0; arr < 4; ++arr)
#pragma unroll
            for (int nt = 0; nt < 4; ++nt) {
                bP[arr][nt][0] = sHCp[arr][nt * 8 + kg * 2];
                bP[arr][nt][1] = sHCp[arr][nt * 8 + kg * 2 + 1];
            }
        unsigned int bB2[4][2];  // b2[PHI] pairs for epilogue (mt, q)
#pragma unroll
        for (int mt = 0; mt < 4; ++mt) {
            bB2[mt][0] = sB2p[mt * 8 + kg * 2];
            bB2[mt][1] = sB2p[mt * 8 + kg * 2 + 1];
        }

        // ===== [3] edge phase =====
        for (int jt = lw; jt < NTILE; jt += 4) {
            int e0 = jt * 16;
            int e = e0 + n0;
            bool vr = e < NE;
            int ec = vr ? e : (NE - 1);
            int a = ec % PP, r = ec / PP;
            int b = (r < a) ? r : r + 1;
            float4 xa = *(const float4*)&sx[gi][a][0];
            float4 xb = *(const float4*)&sx[gi][b][0];
            float4 oa = *(const float4*)&sx0[gi][a][0];
            float4 ob = *(const float4*)&sx0[gi][b][0];
            float dx = xa.x - xb.x, dy = xa.y - xb.y, dz = xa.z - xb.z;
            float rad = dx * dx + dy * dy + dz * dz;
            float ex = oa.x - ob.x, ey = oa.y - ob.y, ez = oa.z - ob.z;
            float ea = ex * ex + ey * ey + ez * ez;
            float inv = __builtin_amdgcn_rcpf(sqrtf(rad + 1e-8f) + 1.0f);
            float cdx = dx * inv, cdy = dy * inv, cdz = dz * inv;
            float cx = xa.y * xb.z - xa.z * xb.y;
            float cy = xa.z * xb.x - xa.x * xb.z;
            float cz = xa.x * xb.y - xa.y * xb.x;
            float cn = __builtin_amdgcn_rcpf(sqrtf(cx * cx + cy * cy + cz * cz + 1e-8f) + 1.0f);
            float crx = cx * cn, cry = cy * cn, crz = cz * cn;

            // ---- E2 (swapped, phi rows): lane n0 = its edge column ----
            f32x4 acc[4];
#pragma unroll
            for (int mt = 0; mt < 4; ++mt) acc[mt] = (f32x4){0.f, 0.f, 0.f, 0.f};
#pragma unroll
            for (int kt = 0; kt < 2; ++kt) {
                int base = kt * 32 + kg * 8;
                bf16x8 av16 = *(const bf16x8*)&sApre[gi][a][base];
                bf16x8 bv16 = *(const bf16x8*)&sBpre[gi][b][base];
                float w8[8], w9[8];
                LD8(w8, &sW128[base]);
                LD8(w9, &sW129[base]);
                bf16x8 zhi;
#pragma unroll
                for (int j8 = 0; j8 < 8; ++j8) {
                    float avf = bf2fs((unsigned short)av16[j8]);
                    float bvf = bf2fs((unsigned short)bv16[j8]);
                    float z = avf + bvf + rad * w8[j8] + ea * w9[j8];
                    zhi[j8] = (short)f2bf(silu_f(z));
                }
#pragma unroll
                for (int mt = 0; mt < 4; ++mt)
                    acc[mt] = MFMA(wE2r[kt][mt], zhi, acc[mt]);
            }
            // epilogue: silu+bias(reg), mask, seg atomics, pack hi
            unsigned short pkE[4][4];
#pragma unroll
            for (int mt = 0; mt < 4; ++mt) {
                int phib = ((mt >> 1) << 5) + (kg << 3) + ((mt & 1) << 2);
#pragma unroll
                for (int q = 0; q < 4; ++q) {
                    float v = silu_f(acc[mt][q] + bfbits(bB2[mt][q >> 1], q & 1));
                    v = vr ? v : 0.f;
                    pkE[mt][q] = f2bf(v);
                    if (vr) atomicAdd(&sSeg[gi][a][phib + q], v);
                }
            }
            // ---- E3 B-frags (EF as B operand): register relabel of pkE ----
            bf16x8 ehi[2];
#pragma unroll
            for (int kt = 0; kt < 2; ++kt)
#pragma unroll
                for (int j8 = 0; j8 < 8; ++j8)
                    ehi[kt][j8] = (short)pkE[kt * 2 + (j8 >> 2)][j8 & 3];

            // ---- E3 (operand-swapped): am[q] = cm1[edge n0][nt*16+kg*4+q] ----
            float pm = 0.f, pc = 0.f;
#pragma unroll
            for (int nt = 0; nt < 4; ++nt) {
                f32x4 am = (f32x4){0.f, 0.f, 0.f, 0.f};
                f32x4 ac = (f32x4){0.f, 0.f, 0.f, 0.f};
#pragma unroll
                for (int kt = 0; kt < 2; ++kt) {
                    am = MFMA(wCMr[kt][nt], ehi[kt], am);
                    ac = MFMA(wCCr[kt][nt], ehi[kt], ac);
                }
#pragma unroll
                for (int q = 0; q < 4; ++q) {
                    int hi = q & 1, pj = q >> 1;
                    float cmb = bfbits(bP[0][nt][pj], hi);
                    float ccb = bfbits(bP[1][nt][pj], hi);
                    float cm2 = bfbits(bP[2][nt][pj], hi);
                    float cc2 = bfbits(bP[3][nt][pj], hi);
                    pm += silu_f(am[q] + cmb) * cm2;
                    pc += silu_f(ac[q] + ccb) * cc2;
                }
            }
            // reduce across kg groups only (lane bits 4,5)
            pm += __shfl_xor(pm, 16, 64);
            pm += __shfl_xor(pm, 32, 64);
            pc += __shfl_xor(pc, 16, 64);
            pc += __shfl_xor(pc, 32, 64);
            if (kg == 0 && vr) {
                atomicAdd(&sTr[gi][a][0], cdx * pm + pc * crx);
                atomicAdd(&sTr[gi][a][1], cdy * pm + pc * cry);
                atomicAdd(&sTr[gi][a][2], cdz * pm + pc * crz);
            }
            // anti-pipelining fence (R12: removal -> 1.4GB scratch spill)
            __builtin_amdgcn_sched_barrier(0);
        }
        __syncthreads();  // s3

        // ===== [4] stage node frags NW1/NW2 (24KB) =====
        STAGE(wfl + 40 * 512, 1536);
        __syncthreads();  // s4

        // ===== [5] node MLP stage 1 (swapped, phi rows) =====
        unsigned short pkN[4][4];
        {
            int mtn = lw >> 1;
            int node = mtn * 16 + n0;
            bool vn = node < PP;
            int crow = vn ? node : 0;
            f32x4 acc[4];
#pragma unroll
            for (int mt = 0; mt < 4; ++mt) acc[mt] = (f32x4){0.f, 0.f, 0.f, 0.f};
#pragma unroll
            for (int kt = 0; kt < 4; ++kt) {
                const float* srcp = (kt < 2) ? &sh[gi][crow][kt * 32 + kg * 8]
                                             : &sSeg[gi][crow][(kt - 2) * 32 + kg * 8];
                float vv[8];
                LD8(vv, srcp);
                bf16x8 bhi;
#pragma unroll
                for (int j8 = 0; j8 < 8; ++j8)
                    bhi[j8] = (short)f2bf(vn ? vv[j8] : 0.f);
#pragma unroll
                for (int mt = 0; mt < 4; ++mt) {
                    bf16x8 wv = *(const bf16x8*)&wlds[(kt * 4 + mt) * 512 + lane * 8];
                    acc[mt] = MFMA(wv, bhi, acc[mt]);
                }
            }
#pragma unroll
            for (int mt = 0; mt < 4; ++mt)
#pragma unroll
                for (int q = 0; q < 4; ++q)
                    pkN[mt][q] = f2bf(silu_f(acc[mt][q] + sBp[64 + mt * 16 + kg * 4 + q]));
        }
        __syncthreads();  // s5

        // ===== [6] node MLP stage 2 + h/x update + cleanup =====
        {
            bf16x8 mh[2];
#pragma unroll
            for (int kt = 0; kt < 2; ++kt)
#pragma unroll
                for (int j8 = 0; j8 < 8; ++j8)
                    mh[kt][j8] = (short)pkN[kt * 2 + (j8 >> 2)][j8 & 3];
            int mtn = lw >> 1;
#pragma unroll
            for (int t = 0; t < 2; ++t) {
                int ntf = (lw & 1) * 2 + t;
                f32x4 acc = (f32x4){0.f, 0.f, 0.f, 0.f};
#pragma unroll
                for (int kt = 0; kt < 2; ++kt) {
                    bf16x8 wv = *(const bf16x8*)&wlds[(16 + kt * 4 + ntf) * 512 + lane * 8];
                    acc = MFMA(mh[kt], wv, acc);
                }
                int col = ntf * 16 + n0;
                float nb2 = node_b2[l * HH + col];
#pragma unroll
                for (int q = 0; q < 4; ++q) {
                    int m = mtn * 16 + kg * 4 + q;
                    if (m < PP) sh[gi][m][col] += acc[q] + nb2;
                }
            }
        }
        if (tid < NG * PP * 4) {
            int gg = tid / (PP * 4), j = tid % (PP * 4);
            int p = j >> 2, d = j & 3;
            float v = sTr[gg][p][d];
            if (d < 3) sx[gg][p][d] += v;
            sTr[gg][p][d] = 0.f;
        }
        for (int idx = tid; idx < NG * PP * SST; idx += 512) (&sSeg[0][0][0])[idx] = 0.f;
        __syncthreads();  // s6: protect wlds/sSeg/sTr before next layer
    }

    // ---- output: vel = (x - x0) - mean_p(x - x0), all graphs ----
    if (tid < NG * 3) {
        int gg = tid / 3, d = tid % 3;
        float s = 0.0f;
        for (int p = 0; p < PP; ++p) s += sx[gg][p][d] - sx0[gg][p][d];
        smean[gg][d] = s / (float)PP;
    }
    __syncthreads();
    if (tid < NG * PP * 3) {
        int gg = tid / (PP * 3), j = tid % (PP * 3);
        int p = j / 3, d = j % 3;
        out[(g0 + gg) * (PP * 3) + j] = (sx[gg][p][d] - sx0[gg][p][d]) - smean[gg][d];
    }
#undef STAGE
}

extern "C" void kernel_launch(void* const* d_in, const int* in_sizes, int n_in,
                              void* d_out, int out_size, void* d_ws, size_t ws_size,
                              hipStream_t stream) {
    const float* input   = (const float*)d_in[0];
    const float* timev   = (const float*)d_in[1];
    const float* emb_w   = (const float*)d_in[2];
    const float* emb_b   = (const float*)d_in[3];
    const float* edge_w1 = (const float*)d_in[4];
    const float* edge_b1 = (const float*)d_in[5];
    const float* edge_w2 = (const float*)d_in[6];
    const float* edge_b2 = (const float*)d_in[7];
    const float* node_w1 = (const float*)d_in[8];
    const float* node_b1 = (const float*)d_in[9];
    const float* node_w2 = (const float*)d_in[10];
    const float* node_b2 = (const float*)d_in[11];
    const float* cm_w1   = (const float*)d_in[12];
    const float* cm_b1   = (const float*)d_in[13];
    const float* cm_w2   = (const float*)d_in[14];
    const float* cc_w1   = (const float*)d_in[15];
    const float* cc_b1   = (const float*)d_in[16];
    const float* cc_w2   = (const float*)d_in[17];
    // d_in[18]=row, d_in[19]=col: deterministic fully-connected edges, recomputed in-kernel

    unsigned short* wsu = (unsigned short*)d_ws;
    prep_w<<<dim3(NL * 64), dim3(64), 0, stream>>>(edge_w1, edge_w2, cm_w1, cc_w1,
                                                   node_w1, node_w2, wsu);

    float* out = (float*)d_out;
    egnn_kernel<<<dim3(1024 / NG), dim3(512), 0, stream>>>(
        input, timev, emb_w, emb_b, edge_w1, edge_b1, edge_b2,
        node_b1, node_b2, cm_b1, cm_w2, cc_b1, cc_w2, wsu, out);
}

// Round 21
// 747.292 us; speedup vs baseline: 1.0396x; 1.0022x over previous
//
#include <hip/hip_runtime.h>
#include <hip/hip_bf16.h>
#include <math.h>

#define PP 22
#define HH 64
#define NL 4
#define NE 462     // 22*21 directed edges, r-major: e = r*22 + a
#define NTILE 29   // ceil(462/16)
#define SST 68     // float stride for node-feature rows (sh, sSeg)
#define SSTH 72    // ushort stride for bf16 Apre/Bpre rows
#define NG 2       // graphs per block

typedef __attribute__((ext_vector_type(8))) short bf16x8;
typedef __attribute__((ext_vector_type(4))) float f32x4;

#define MFMA(A, B, C) __builtin_amdgcn_mfma_f32_16x16x32_bf16(A, B, C, 0, 0, 0)
#define PHI(mt, r) ((((mt) >> 1) << 5) + (((r) >> 2) << 3) + (((mt) & 1) << 2) + ((r) & 3))

// fast silu: v_exp + v_rcp (hardware approx, ~2^-22 rel err)
__device__ __forceinline__ float silu_f(float v) {
    return v * __builtin_amdgcn_rcpf(1.0f + __expf(-v));
}

__device__ __forceinline__ unsigned short f2bf(float x) {
    __hip_bfloat16 h = __float2bfloat16(x);
    unsigned short u;
    __builtin_memcpy(&u, &h, 2);
    return u;
}
__device__ __forceinline__ float bf2fs(unsigned short h) {
    return __uint_as_float(((unsigned int)h) << 16);
}
__device__ __forceinline__ float bfbits(unsigned int u, int hi) {
    return __uint_as_float(((u >> (hi * 16)) & 0xffffu) << 16);
}

#define LD8(dst, PTR) { \
    float4 _a = *(const float4*)(PTR); float4 _b = *(const float4*)((PTR) + 4); \
    dst[0]=_a.x; dst[1]=_a.y; dst[2]=_a.z; dst[3]=_a.w; \
    dst[4]=_b.x; dst[5]=_b.y; dst[6]=_b.z; dst[7]=_b.w; }

// ---------------------------------------------------------------------------
// Weight prep (unchanged): hi-only bf16 frag blocks, 512 ushorts each.
//  0-7 W1a | 8-15 W1b | 16-23 W2 phi | 24-31 CM1 | 32-39 CC1 | 40-55 NW1 phi | 56-63 NW2
// ---------------------------------------------------------------------------
__global__ __launch_bounds__(64) void prep_w(
    const float* __restrict__ edge_w1, const float* __restrict__ edge_w2,
    const float* __restrict__ cm_w1, const float* __restrict__ cc_w1,
    const float* __restrict__ node_w1, const float* __restrict__ node_w2,
    unsigned short* __restrict__ ws)
{
    int blk = blockIdx.x;
    int l = blk >> 6, moff = blk & 63;
    int lane = threadIdx.x, n0 = lane & 15, kg = lane >> 4;
    const float* base; int col, kt;
    if (moff < 8)       { kt = moff >> 2;              int nt = moff & 3;        base = edge_w1 + l * 130 * HH;           col = nt * 16 + n0; }
    else if (moff < 16) { int m = moff - 8;  kt = m >> 2; int nt = m & 3;        base = edge_w1 + l * 130 * HH + 64 * HH; col = nt * 16 + n0; }
    else if (moff < 24) { int m = moff - 16; kt = m >> 2; int mt = m & 3;        base = edge_w2 + l * HH * HH;            col = PHI(mt, n0); }
    else if (moff < 32) { int m = moff - 24; kt = m >> 2; int nt = m & 3;        base = cm_w1 + l * HH * HH;              col = nt * 16 + n0; }
    else if (moff < 40) { int m = moff - 32; kt = m >> 2; int nt = m & 3;        base = cc_w1 + l * HH * HH;              col = nt * 16 + n0; }
    else if (moff < 56) { int m = moff - 40; kt = m >> 2; int mt = m & 3;        base = node_w1 + l * 128 * HH;           col = PHI(mt, n0); }
    else                { int m = moff - 56; kt = m >> 2; int nt = m & 3;        base = node_w2 + l * HH * HH;            col = nt * 16 + n0; }
    int k0 = kt * 32 + kg * 8;
    unsigned short* d = ws + blk * 512 + lane * 8;
#pragma unroll
    for (int j = 0; j < 8; ++j) d[j] = f2bf(base[(k0 + j) * HH + col]);
}

// ---------------------------------------------------------------------------
// Main kernel: TWO graphs per block, 512 threads (8 waves: 4 per graph),
// ~64KB LDS. Unified RF (128 VGPR + AGPR weight preload ~ 256/wave) caps
// occupancy at 2 waves/SIMD -> cross-iteration ILP is the remaining lever:
// sched_barrier(0x104) allows DS_READ+SALU (next tile's load prefetch) to
// cross the iteration boundary while pinning VALU/MFMA/DS_WRITE (mask 0 was
// fully serial; no fence at all spilled 1.4GB in R12).
// ---------------------------------------------------------------------------
__global__ __launch_bounds__(512, 1) void egnn_kernel(
    const float* __restrict__ input, const float* __restrict__ timev,
    const float* __restrict__ emb_w, const float* __restrict__ emb_b,
    const float* __restrict__ edge_w1, const float* __restrict__ edge_b1,
    const float* __restrict__ edge_b2,
    const float* __restrict__ node_b1, const float* __restrict__ node_b2,
    const float* __restrict__ cm_b1, const float* __restrict__ cm_w2,
    const float* __restrict__ cc_b1, const float* __restrict__ cc_w2,
    const unsigned short* __restrict__ wfr,
    float* __restrict__ out)
{
    const int g0   = blockIdx.x * NG;
    const int tid  = threadIdx.x;
    const int w    = tid >> 6;     // wave 0..7
    const int lw   = w & 3;        // wave-local within graph
    const int gi   = w >> 2;       // graph index 0..1
    const int lane = tid & 63;
    const int n0   = lane & 15;
    const int kg   = lane >> 4;

    __shared__ __align__(16) unsigned short wlds[12288];   // 24KB staging
    __shared__ __align__(16) unsigned short sApre[NG][PP][SSTH];  // bf16
    __shared__ __align__(16) unsigned short sBpre[NG][PP][SSTH];  // bf16
    __shared__ float sh[NG][PP][SST], sSeg[NG][PP][SST];
    __shared__ __align__(16) float sx[NG][PP][4];
    __shared__ __align__(16) float sx0[NG][PP][4];
    __shared__ float sTr[NG][PP][4];
    __shared__ float sW128[HH], sW129[HH];
    __shared__ float sBp[128];              // [0..63] b2[PHI], [64..127] nb1[PHI]
    __shared__ unsigned int sB2p[32];       // packed bf16 pairs of b2[PHI]
    __shared__ unsigned int sHCp[4][32];    // packed bf16 pairs: cmb,ccb,cm2,cc2
    __shared__ float smean[NG][3];

#define STAGE(SRC, N16) { const uint4* _s = (const uint4*)(SRC); uint4* _d = (uint4*)wlds; \
    for (int idx = tid; idx < (N16); idx += 512) _d[idx] = _s[idx]; }

    // ---- init ----
    if (tid < NG * PP * 3) {
        int gg = tid / (PP * 3), j = tid % (PP * 3);
        float v = input[(g0 + gg) * (PP * 3) + j];
        sx0[gg][j / 3][j % 3] = v;
        sx [gg][j / 3][j % 3] = v;
    }
    if (tid < NG * PP) { int gg = tid / PP, p = tid % PP; sx0[gg][p][3] = 0.f; sx[gg][p][3] = 0.f; }
    {
        float tg = timev[g0 + gi];
        for (int i = lw; i < PP; i += 4)
            sh[gi][i][lane] = emb_w[i * HH + lane] + tg * emb_w[PP * HH + lane] + emb_b[lane];
    }
    for (int idx = tid; idx < NG * PP * SST; idx += 512) (&sSeg[0][0][0])[idx] = 0.f;
    if (tid < NG * PP * 4) (&sTr[0][0][0])[tid] = 0.f;
    __syncthreads();

    for (int l = 0; l < NL; ++l) {
        const unsigned short* wfl = wfr + (size_t)l * 32768;

        // ===== [1] stage W1a/W1b frags (16KB) + per-layer constants =====
        STAGE(wfl, 1024);
        if (tid < HH)               sW128[tid]        = edge_w1[(l * 130 + 128) * HH + tid];
        else if (tid < 2 * HH)      sW129[tid - HH]   = edge_w1[(l * 130 + 129) * HH + tid - HH];
        else if (tid < 2 * HH + 128) {
            int t2 = tid - 2 * HH;
            int i = t2 & 63, mt = i >> 4, r = i & 15;
            int phi = PHI(mt, r);
            sBp[t2] = (t2 < 64) ? edge_b2[l * HH + phi] : node_b1[l * HH + phi];
        } else if (tid < 2 * HH + 128 + 128) {
            int t3 = tid - (2 * HH + 128);          // 0..127
            int arr = t3 >> 5, j = t3 & 31;
            const float* src = (arr == 0) ? cm_b1 : (arr == 1) ? cc_b1 : (arr == 2) ? cm_w2 : cc_w2;
            sHCp[arr][j] = (unsigned)f2bf(src[l * HH + 2 * j])
                         | ((unsigned)f2bf(src[l * HH + 2 * j + 1]) << 16);
        } else if (tid < 2 * HH + 128 + 128 + 32) {
            int j = tid - (2 * HH + 128 + 128);     // 0..31: pack b2[PHI] pairs
            int i0 = 2 * j, i1 = 2 * j + 1;
            int phi0 = PHI(i0 >> 4, i0 & 15), phi1 = PHI(i1 >> 4, i1 & 15);
            sB2p[j] = (unsigned)f2bf(edge_b2[l * HH + phi0])
                    | ((unsigned)f2bf(edge_b2[l * HH + phi1]) << 16);
        }
        __syncthreads();  // s1

        // ===== [2] Apre/Bpre via MFMA (stored bf16): (mtn, mat)=(lw&1,lw>>1)
        {
            int mtn = lw & 1, mat = lw >> 1;
            int node = mtn * 16 + n0;
            bool vn = node < PP;
            int crow = vn ? node : 0;
            bf16x8 hhi[2];
#pragma unroll
            for (int kt = 0; kt < 2; ++kt) {
                float vv[8];
                LD8(vv, &sh[gi][crow][kt * 32 + kg * 8]);
#pragma unroll
                for (int j = 0; j < 8; ++j)
                    hhi[kt][j] = (short)f2bf(vn ? vv[j] : 0.f);
            }
#pragma unroll
            for (int ntf = 0; ntf < 4; ++ntf) {
                f32x4 acc = (f32x4){0.f, 0.f, 0.f, 0.f};
#pragma unroll
                for (int kt = 0; kt < 2; ++kt) {
                    bf16x8 wv = *(const bf16x8*)&wlds[(mat * 8 + kt * 4 + ntf) * 512 + lane * 8];
                    acc = MFMA(hhi[kt], wv, acc);
                }
                int col = ntf * 16 + n0;
                float b1v = edge_b1[l * HH + col];
#pragma unroll
                for (int q = 0; q < 4; ++q) {
                    int m = mtn * 16 + kg * 4 + q;
                    if (m < PP) {
                        if (mat == 0) sApre[gi][m][col] = f2bf(acc[q] + b1v);
                        else          sBpre[gi][m][col] = f2bf(acc[q]);
                    }
                }
            }
        }
        __syncthreads();  // s2

        // ===== [2b] stage edge frags W2/CM1/CC1 (24KB) =====
        STAGE(wfl + 16 * 512, 1536);
        __syncthreads();  // s2b

        // ---- register-resident edge weights + packed consts ----
        bf16x8 wE2r[2][4], wCMr[2][4], wCCr[2][4];
#pragma unroll
        for (int kt = 0; kt < 2; ++kt)
#pragma unroll
            for (int mt = 0; mt < 4; ++mt) {
                wE2r[kt][mt] = *(const bf16x8*)&wlds[(kt * 4 + mt) * 512 + lane * 8];
                wCMr[kt][mt] = *(const bf16x8*)&wlds[(8 + kt * 4 + mt) * 512 + lane * 8];
                wCCr[kt][mt] = *(const bf16x8*)&wlds[(16 + kt * 4 + mt) * 512 + lane * 8];
            }
        unsigned int bP[4][4][2];
#pragma unroll
        for (int arr = 0; arr < 4; ++arr)
#pragma unroll
            for (int nt = 0; nt < 4; ++nt) {
                bP[arr][nt][0] = sHCp[arr][nt * 8 + kg * 2];
                bP[arr][nt][1] = sHCp[arr][nt * 8 + kg * 2 + 1];
            }
        unsigned int bB2[4][2];  // b2[PHI] pairs for epilogue (mt, q)
#pragma unroll
        for (int mt = 0; mt < 4; ++mt) {
            bB2[mt][0] = sB2p[mt * 8 + kg * 2];
            bB2[mt][1] = sB2p[mt * 8 + kg * 2 + 1];
        }

        // ===== [3] edge phase =====
        for (int jt = lw; jt < NTILE; jt += 4) {
            int e0 = jt * 16;
            int e = e0 + n0;
            bool vr = e < NE;
            int ec = vr ? e : (NE - 1);
            int a = ec % PP, r = ec / PP;
            int b = (r < a) ? r : r + 1;
            float4 xa = *(const float4*)&sx[gi][a][0];
            float4 xb = *(const float4*)&sx[gi][b][0];
            float4 oa = *(const float4*)&sx0[gi][a][0];
            float4 ob = *(const float4*)&sx0[gi][b][0];
            float dx = xa.x - xb.x, dy = xa.y - xb.y, dz = xa.z - xb.z;
            float rad = dx * dx + dy * dy + dz * dz;
            float ex = oa.x - ob.x, ey = oa.y - ob.y, ez = oa.z - ob.z;
            float ea = ex * ex + ey * ey + ez * ez;
            float inv = __builtin_amdgcn_rcpf(sqrtf(rad + 1e-8f) + 1.0f);
            float cdx = dx * inv, cdy = dy * inv, cdz = dz * inv;
            float cx = xa.y * xb.z - xa.z * xb.y;
            float cy = xa.z * xb.x - xa.x * xb.z;
            float cz = xa.x * xb.y - xa.y * xb.x;
            float cn = __builtin_amdgcn_rcpf(sqrtf(cx * cx + cy * cy + cz * cz + 1e-8f) + 1.0f);
            float crx = cx * cn, cry = cy * cn, crz = cz * cn;

            // ---- E2 (swapped, phi rows): lane n0 = its edge column ----
            f32x4 acc[4];
#pragma unroll
            for (int mt = 0; mt < 4; ++mt) acc[mt] = (f32x4){0.f, 0.f, 0.f, 0.f};
#pragma unroll
            for (int kt = 0; kt < 2; ++kt) {
                int base = kt * 32 + kg * 8;
                bf16x8 av16 = *(const bf16x8*)&sApre[gi][a][base];
                bf16x8 bv16 = *(const bf16x8*)&sBpre[gi][b][base];
                float w8[8], w9[8];
                LD8(w8, &sW128[base]);
                LD8(w9, &sW129[base]);
                bf16x8 zhi;
#pragma unroll
                for (int j8 = 0; j8 < 8; ++j8) {
                    float avf = bf2fs((unsigned short)av16[j8]);
                    float bvf = bf2fs((unsigned short)bv16[j8]);
                    float z = avf + bvf + rad * w8[j8] + ea * w9[j8];
                    zhi[j8] = (short)f2bf(silu_f(z));
                }
#pragma unroll
                for (int mt = 0; mt < 4; ++mt)
                    acc[mt] = MFMA(wE2r[kt][mt], zhi, acc[mt]);
            }
            // epilogue: silu+bias(reg), mask, seg atomics, pack hi
            unsigned short pkE[4][4];
#pragma unroll
            for (int mt = 0; mt < 4; ++mt) {
                int phib = ((mt >> 1) << 5) + (kg << 3) + ((mt & 1) << 2);
#pragma unroll
                for (int q = 0; q < 4; ++q) {
                    float v = silu_f(acc[mt][q] + bfbits(bB2[mt][q >> 1], q & 1));
                    v = vr ? v : 0.f;
                    pkE[mt][q] = f2bf(v);
                    if (vr) atomicAdd(&sSeg[gi][a][phib + q], v);
                }
            }
            // ---- E3 B-frags (EF as B operand): register relabel of pkE ----
            bf16x8 ehi[2];
#pragma unroll
            for (int kt = 0; kt < 2; ++kt)
#pragma unroll
                for (int j8 = 0; j8 < 8; ++j8)
                    ehi[kt][j8] = (short)pkE[kt * 2 + (j8 >> 2)][j8 & 3];

            // ---- E3 (operand-swapped): am[q] = cm1[edge n0][nt*16+kg*4+q] ----
            float pm = 0.f, pc = 0.f;
#pragma unroll
            for (int nt = 0; nt < 4; ++nt) {
                f32x4 am = (f32x4){0.f, 0.f, 0.f, 0.f};
                f32x4 ac = (f32x4){0.f, 0.f, 0.f, 0.f};
#pragma unroll
                for (int kt = 0; kt < 2; ++kt) {
                    am = MFMA(wCMr[kt][nt], ehi[kt], am);
                    ac = MFMA(wCCr[kt][nt], ehi[kt], ac);
                }
#pragma unroll
                for (int q = 0; q < 4; ++q) {
                    int hi = q & 1, pj = q >> 1;
                    float cmb = bfbits(bP[0][nt][pj], hi);
                    float ccb = bfbits(bP[1][nt][pj], hi);
                    float cm2 = bfbits(bP[2][nt][pj], hi);
                    float cc2 = bfbits(bP[3][nt][pj], hi);
                    pm += silu_f(am[q] + cmb) * cm2;
                    pc += silu_f(ac[q] + ccb) * cc2;
                }
            }
            // reduce across kg groups only (lane bits 4,5)
            pm += __shfl_xor(pm, 16, 64);
            pm += __shfl_xor(pm, 32, 64);
            pc += __shfl_xor(pc, 16, 64);
            pc += __shfl_xor(pc, 32, 64);
            if (kg == 0 && vr) {
                atomicAdd(&sTr[gi][a][0], cdx * pm + pc * crx);
                atomicAdd(&sTr[gi][a][1], cdy * pm + pc * cry);
                atomicAdd(&sTr[gi][a][2], cdz * pm + pc * crz);
            }
            // selective fence: pin VALU/MFMA/DS_WRITE to this iteration but
            // let DS_READ(0x100)+SALU(0x4) cross -> next tile's loads prefetch
            // under current compute. (mask 0 = fully serial chains, R13-R20;
            // no fence = full pipelining -> 1.4GB spill, R12.)
            __builtin_amdgcn_sched_barrier(0x104);
        }
        __syncthreads();  // s3

        // ===== [4] stage node frags NW1/NW2 (24KB) =====
        STAGE(wfl + 40 * 512, 1536);
        __syncthreads();  // s4

        // ===== [5] node MLP stage 1 (swapped, phi rows) =====
        unsigned short pkN[4][4];
        {
            int mtn = lw >> 1;
            int node = mtn * 16 + n0;
            bool vn = node < PP;
            int crow = vn ? node : 0;
            f32x4 acc[4];
#pragma unroll
            for (int mt = 0; mt < 4; ++mt) acc[mt] = (f32x4){0.f, 0.f, 0.f, 0.f};
#pragma unroll
            for (int kt = 0; kt < 4; ++kt) {
                const float* srcp = (kt < 2) ? &sh[gi][crow][kt * 32 + kg * 8]
                                             : &sSeg[gi][crow][(kt - 2) * 32 + kg * 8];
                float vv[8];
                LD8(vv, srcp);
                bf16x8 bhi;
#pragma unroll
                for (int j8 = 0; j8 < 8; ++j8)
                    bhi[j8] = (short)f2bf(vn ? vv[j8] : 0.f);
#pragma unroll
                for (int mt = 0; mt < 4; ++mt) {
                    bf16x8 wv = *(const bf16x8*)&wlds[(kt * 4 + mt) * 512 + lane * 8];
                    acc[mt] = MFMA(wv, bhi, acc[mt]);
                }
            }
#pragma unroll
            for (int mt = 0; mt < 4; ++mt)
#pragma unroll
                for (int q = 0; q < 4; ++q)
                    pkN[mt][q] = f2bf(silu_f(acc[mt][q] + sBp[64 + mt * 16 + kg * 4 + q]));
        }
        __syncthreads();  // s5

        // ===== [6] node MLP stage 2 + h/x update + cleanup =====
        {
            bf16x8 mh[2];
#pragma unroll
            for (int kt = 0; kt < 2; ++kt)
#pragma unroll
                for (int j8 = 0; j8 < 8; ++j8)
                    mh[kt][j8] = (short)pkN[kt * 2 + (j8 >> 2)][j8 & 3];
            int mtn = lw >> 1;
#pragma unroll
            for (int t = 0; t < 2; ++t) {
                int ntf = (lw & 1) * 2 + t;
                f32x4 acc = (f32x4){0.f, 0.f, 0.f, 0.f};
#pragma unroll
                for (int kt = 0; kt < 2; ++kt) {
                    bf16x8 wv = *(const bf16x8*)&wlds[(16 + kt * 4 + ntf) * 512 + lane * 8];
                    acc = MFMA(mh[kt], wv, acc);
                }
                int col = ntf * 16 + n0;
                float nb2 = node_b2[l * HH + col];
#pragma unroll
                for (int q = 0; q < 4; ++q) {
                    int m = mtn * 16 + kg * 4 + q;
                    if (m < PP) sh[gi][m][col] += acc[q] + nb2;
                }
            }
        }
        if (tid < NG * PP * 4) {
            int gg = tid / (PP * 4), j = tid % (PP * 4);
            int p = j >> 2, d = j & 3;
            float v = sTr[gg][p][d];
            if (d < 3) sx[gg][p][d] += v;
            sTr[gg][p][d] = 0.f;
        }
        for (int idx = tid; idx < NG * PP * SST; idx += 512) (&sSeg[0][0][0])[idx] = 0.f;
        __syncthreads();  // s6: protect wlds/sSeg/sTr before next layer
    }

    // ---- output: vel = (x - x0) - mean_p(x - x0), all graphs ----
    if (tid < NG * 3) {
        int gg = tid / 3, d = tid % 3;
        float s = 0.0f;
        for (int p = 0; p < PP; ++p) s += sx[gg][p][d] - sx0[gg][p][d];
        smean[gg][d] = s / (float)PP;
    }
    __syncthreads();
    if (tid < NG * PP * 3) {
        int gg = tid / (PP * 3), j = tid % (PP * 3);
        int p = j / 3, d = j % 3;
        out[(g0 + gg) * (PP * 3) + j] = (sx[gg][p][d] - sx0[gg][p][d]) - smean[gg][d];
    }
#undef STAGE
}

extern "C" void kernel_launch(void* const* d_in, const int* in_sizes, int n_in,
                              void* d_out, int out_size, void* d_ws, size_t ws_size,
                              hipStream_t stream) {
    const float* input   = (const float*)d_in[0];
    const float* timev   = (const float*)d_in[1];
    const float* emb_w   = (const float*)d_in[2];
    const float* emb_b   = (const float*)d_in[3];
    const float* edge_w1 = (const float*)d_in[4];
    const float* edge_b1 = (const float*)d_in[5];
    const float* edge_w2 = (const float*)d_in[6];
    const float* edge_b2 = (const float*)d_in[7];
    const float* node_w1 = (const float*)d_in[8];
    const float* node_b1 = (const float*)d_in[9];
    const float* node_w2 = (const float*)d_in[10];
    const float* node_b2 = (const float*)d_in[11];
    const float* cm_w1   = (const float*)d_in[12];
    const float* cm_b1   = (const float*)d_in[13];
    const float* cm_w2   = (const float*)d_in[14];
    const float* cc_w1   = (const float*)d_in[15];
    const float* cc_b1   = (const float*)d_in[16];
    const float* cc_w2   = (const float*)d_in[17];
    // d_in[18]=row, d_in[19]=col: deterministic fully-connected edges, recomputed in-kernel

    unsigned short* wsu = (unsigned short*)d_ws;
    prep_w<<<dim3(NL * 64), dim3(64), 0, stream>>>(edge_w1, edge_w2, cm_w1, cc_w1,
                                                   node_w1, node_w2, wsu);

    float* out = (float*)d_out;
    egnn_kernel<<<dim3(1024 / NG), dim3(512), 0, stream>>>(
        input, timev, emb_w, emb_b, edge_w1, edge_b1, edge_b2,
        node_b1, node_b2, cm_b1, cm_w2, cc_b1, cc_w2, wsu, out);
}